// Round 1
// baseline (1131.591 us; speedup 1.0000x reference)
//
#include <hip/hip_runtime.h>
#include <hip/hip_bf16.h>

// loss = -sum_i log(predictions[i, targets[i]]), B=262144, V=1024
// predictions: float32 [B,V]; targets: int32 [B] (harness delivers ints as int32)
// output: single float32 scalar.

#define B_ROWS 262144
#define V_COLS 1024

__global__ __launch_bounds__(256) void nll_gather_reduce(
    const float* __restrict__ pred,
    const int* __restrict__ tgt,
    float* __restrict__ out)
{
    int tid = blockIdx.x * blockDim.x + threadIdx.x;
    int stride = gridDim.x * blockDim.x;

    float local = 0.0f;
    for (int i = tid; i < B_ROWS; i += stride) {
        int t = tgt[i];
        float p = pred[(size_t)i * V_COLS + t];
        local += __logf(p);
    }

    // wave-64 reduction
    for (int off = 32; off > 0; off >>= 1)
        local += __shfl_down(local, off, 64);

    // cross-wave via LDS (256 threads = 4 waves)
    __shared__ float wsum[4];
    int lane = threadIdx.x & 63;
    int wave = threadIdx.x >> 6;
    if (lane == 0) wsum[wave] = local;
    __syncthreads();

    if (threadIdx.x == 0) {
        float s = wsum[0] + wsum[1] + wsum[2] + wsum[3];
        atomicAdd(out, -s);
    }
}

extern "C" void kernel_launch(void* const* d_in, const int* in_sizes, int n_in,
                              void* d_out, int out_size, void* d_ws, size_t ws_size,
                              hipStream_t stream) {
    const float* pred = (const float*)d_in[0];
    const int*   tgt  = (const int*)d_in[1];
    float* out = (float*)d_out;

    // d_out is re-poisoned to 0xAA before every timed launch — zero it here.
    hipMemsetAsync(out, 0, sizeof(float), stream);

    // 1024 blocks x 256 threads = 262144 threads, one row each.
    nll_gather_reduce<<<1024, 256, 0, stream>>>(pred, tgt, out);
}